// Round 12
// baseline (392.412 us; speedup 1.0000x reference)
//
#include <hip/hip_runtime.h>

#define NVEC 65536   // B*H*W = 64*32*32
#define KCB  1024
#define DIM  128
#define HW   1024    // H*W
#define CHUNK 64
#define NCHUNKS (NVEC / CHUNK)

typedef __bf16 b16;
typedef b16 b16x8 __attribute__((ext_vector_type(8)));
typedef float f32x16 __attribute__((ext_vector_type(16)));

static __device__ __forceinline__ unsigned short f2bf(float f) {
  unsigned int x = __float_as_uint(f);
  unsigned int r = x + 0x7fffu + ((x >> 16) & 1u);   // RNE
  return (unsigned short)(r >> 16);
}

// ---- fused prep: cbt pack + out6=0.99*emw + hist=0 + ccb(f32) + cc64(f64) -
__global__ void k_prep(const float* __restrict__ cb, const float* __restrict__ emw,
                       uint4* __restrict__ cbt, float* __restrict__ ccb,
                       double* __restrict__ cc64, float* __restrict__ out6,
                       int* __restrict__ hist) {
  const int t = blockIdx.x * blockDim.x + threadIdx.x;   // 16384
  const int kc = t >> 11, u = t & 2047;
  const int code7 = u & 127, dch = u >> 7;
  const float* src = cb + (kc * 128 + code7) * 128 + dch * 8;
  const float4 x = *(const float4*)src;
  const float4 y = *(const float4*)(src + 4);
  uint4 o;
  o.x = (unsigned)f2bf(x.x) | ((unsigned)f2bf(x.y) << 16);
  o.y = (unsigned)f2bf(x.z) | ((unsigned)f2bf(x.w) << 16);
  o.z = (unsigned)f2bf(y.x) | ((unsigned)f2bf(y.y) << 16);
  o.w = (unsigned)f2bf(y.z) | ((unsigned)f2bf(y.w) << 16);
  cbt[t] = o;
  // out6 init: out6 offset is 8B- but not 16B-aligned -> float2 stores
  const float4 e0 = *(const float4*)(emw + (size_t)t * 8);
  const float4 e1 = *(const float4*)(emw + (size_t)t * 8 + 4);
  *(float2*)(out6 + (size_t)t * 8 + 0) = make_float2(0.99f * e0.x, 0.99f * e0.y);
  *(float2*)(out6 + (size_t)t * 8 + 2) = make_float2(0.99f * e0.z, 0.99f * e0.w);
  *(float2*)(out6 + (size_t)t * 8 + 4) = make_float2(0.99f * e1.x, 0.99f * e1.y);
  *(float2*)(out6 + (size_t)t * 8 + 6) = make_float2(0.99f * e1.z, 0.99f * e1.w);
  if (t < KCB) hist[t] = 0;
  if (blockIdx.x < 4) {
    const int k = blockIdx.x * 256 + threadIdx.x;
    const float* row = cb + k * DIM;
    double s = 0.0;
#pragma unroll 8
    for (int j = 0; j < DIM; ++j) {
      const double v = (double)row[j];
      s = fma(v, v, s);
    }
    cc64[k] = s;
    ccb[k] = 512.f - 0.5f * (float)s;   // bias keeps packed scores positive
  }
}

// ---- MFMA argmin + fused transpose; 2-phase double-buffered LDS staging ---
// R10 post-mortem: L2-direct B-tiles spilled (VGPR cap 128 at 4 waves/SIMD).
// Back to LDS staging, but pipelined: 16 chunks of 64 codes (16KB), double
// buffer; per chunk: barrier (drains stage c) -> issue stage c+1 -> compute.
// Staging hides under compute (T3 minimal recipe), one barrier per chunk.
// score(bias) = 512 - cc/2 + dot straight out of MFMA (C-in); positive =>
// u32-monotone; index inverted in low 10 bits (max-tie -> min k).
__global__ __launch_bounds__(256, 4) void k_argmin4(
    const float* __restrict__ z, const uint4* __restrict__ cbt,
    const float* __restrict__ ccb, uint2* __restrict__ pcand,
    float* __restrict__ z_t) {
  __shared__ __align__(16) float zs[128][65];          // 33.3 KB; reused as Bs
  uint4* Bs = (uint4*)zs;                              // [2][16 dch][64 codes]
  const int tid = threadIdx.x;
  const int l = tid & 63, wv = tid >> 6;
  const int g = l >> 5;                            // k-slice group
  const int lm = l & 31;                           // row-lane / code-lane
  const int wr = (wv & 1) * 32;                    // row group
  const int cg = wv >> 1;                          // code col-group in chunk
  const int n0 = blockIdx.x * 64;
  const int b = n0 >> 10;
  const int hwbase = n0 & (HW - 1);

  // ---- phase 0: coalesced stage of the z tile into LDS
  {
    const int hw4 = (tid & 15) * 4;
    const int dr = tid >> 4;
    const float* src = z + (size_t)b * 131072 + hwbase + hw4;
#pragma unroll
    for (int j = 0; j < 8; ++j) {
      const int d = dr + 16 * j;
      const float4 v = *(const float4*)(src + d * 1024);
      zs[d][hw4 + 0] = v.x; zs[d][hw4 + 1] = v.y;
      zs[d][hw4 + 2] = v.z; zs[d][hw4 + 3] = v.w;
    }
  }
  __syncthreads();

  // ---- phase 1a: z_t rows, full-line stores (8 lanes x 16B per 512B row)
#pragma unroll
  for (int jj = 0; jj < 2; ++jj) {
    const int row = (tid >> 3) + 32 * jj;
    float* dst = z_t + ((size_t)(n0 + row)) * 128;
#pragma unroll
    for (int j = 0; j < 4; ++j) {
      const int d = (j * 8 + (tid & 7)) * 4;
      float4 v;
      v.x = zs[d + 0][row]; v.y = zs[d + 1][row];
      v.z = zs[d + 2][row]; v.w = zs[d + 3][row];
      *(float4*)(dst + d) = v;
    }
  }
  // ---- phase 1b: afrag from LDS
  uint4 afrag[8];
  {
    const int row = wr + lm;
#pragma unroll
    for (int ks = 0; ks < 8; ++ks) {
      const int d0 = ks * 16 + g * 8;
      afrag[ks].x = (unsigned)f2bf(zs[d0 + 0][row]) | ((unsigned)f2bf(zs[d0 + 1][row]) << 16);
      afrag[ks].y = (unsigned)f2bf(zs[d0 + 2][row]) | ((unsigned)f2bf(zs[d0 + 3][row]) << 16);
      afrag[ks].z = (unsigned)f2bf(zs[d0 + 4][row]) | ((unsigned)f2bf(zs[d0 + 5][row]) << 16);
      afrag[ks].w = (unsigned)f2bf(zs[d0 + 6][row]) | ((unsigned)f2bf(zs[d0 + 7][row]) << 16);
    }
  }

  // preload per-chunk C-in bias values (ccb is 4KB, cache-hot): 16 regs
  float ccv[16];
#pragma unroll
  for (int c = 0; c < 16; ++c) ccv[c] = ccb[c * 64 + cg * 32 + lm];

  unsigned pm1[16], pm2[16];
#pragma unroll
  for (int r = 0; r < 16; ++r) { pm1[r] = 0u; pm2[r] = 0u; }

  __syncthreads();                     // zs reads done; Bs may overwrite
  // stage chunk 0 into buffer 0: wave wv stages dchunks 4wv..4wv+3
#pragma unroll
  for (int i = 0; i < 4; ++i) {
    const int dch = wv * 4 + i;
    __builtin_amdgcn_global_load_lds(&cbt[0 * 2048 + dch * 128 + 0 * 64 + l],
                                     &Bs[0 * 1024 + dch * 64], 16, 0, 0);
  }

  int cur = 0;
  for (int c = 0; c < 16; ++c) {
    __syncthreads();                   // drains stage(c); buf[cur] ready
    if (c < 15) {                      // issue stage(c+1) -> overlaps compute
      const int kc = (c + 1) >> 1, half = (c + 1) & 1;
#pragma unroll
      for (int i = 0; i < 4; ++i) {
        const int dch = wv * 4 + i;
        __builtin_amdgcn_global_load_lds(&cbt[kc * 2048 + dch * 128 + half * 64 + l],
                                         &Bs[(cur ^ 1) * 1024 + dch * 64], 16, 0, 0);
      }
    }
    f32x16 acc;
#pragma unroll
    for (int j = 0; j < 16; ++j) acc[j] = ccv[c];
#pragma unroll
    for (int ks = 0; ks < 8; ++ks) {
      const b16x8 av = *reinterpret_cast<const b16x8*>(&afrag[ks]);
      const b16x8 bv = *reinterpret_cast<const b16x8*>(
          &Bs[cur * 1024 + (ks * 2 + g) * 64 + cg * 32 + lm]);
      acc = __builtin_amdgcn_mfma_f32_32x32x16_bf16(av, bv, acc, 0, 0, 0);
    }
    const unsigned ci = 1023u - (unsigned)(c * 64 + cg * 32 + lm);
#pragma unroll
    for (int r = 0; r < 16; ++r) {
      const unsigned uu = ((__float_as_uint(acc[r]) + 0x200u) & 0xFFFFFC00u) | ci;
      const unsigned t = pm1[r] < uu ? pm1[r] : uu;
      pm1[r] = pm1[r] > uu ? pm1[r] : uu;
      pm2[r] = pm2[r] > t ? pm2[r] : t;
    }
    cur ^= 1;
  }

  // top-2 (max-order) merge across the 32 code-lanes
#pragma unroll
  for (int r = 0; r < 16; ++r) {
    unsigned u1 = pm1[r], u2 = pm2[r];
#pragma unroll
    for (int m = 1; m < 32; m <<= 1) {
      const unsigned o1 = (unsigned)__shfl_xor((int)u1, m, 64);
      const unsigned o2 = (unsigned)__shfl_xor((int)u2, m, 64);
      const unsigned s = u1 < o1 ? u1 : o1;
      u1 = u1 > o1 ? u1 : o1;
      u2 = u2 > o2 ? u2 : o2;
      u2 = u2 > s ? u2 : s;
    }
    if (lm == 0) {
      const int rowg = n0 + wr + (r & 3) + 8 * (r >> 2) + 4 * g;
      pcand[cg * NVEC + rowg] = make_uint2(u1, u2);
    }
  }
}

// ---- exact f64 rescore of ALL 4 candidates + idx + LDS histogram ----------
__global__ void k_rescore_hist(const float* __restrict__ z_t, const float* __restrict__ cb,
                               const double* __restrict__ cc64,
                               const uint2* __restrict__ pcand,
                               float* __restrict__ out1, int* __restrict__ hist) {
  __shared__ int h[KCB];
  const int tid = threadIdx.x;
#pragma unroll
  for (int j = 0; j < 4; ++j) h[tid + 256 * j] = 0;
  __syncthreads();
  const int n = blockIdx.x * 256 + tid;
  const uint2 A = pcand[n];
  const uint2 Bq = pcand[NVEC + n];
  int ks[4];
  ks[0] = 1023 - (int)(A.x & 1023u);
  ks[1] = 1023 - (int)(A.y & 1023u);
  ks[2] = 1023 - (int)(Bq.x & 1023u);
  ks[3] = 1023 - (int)(Bq.y & 1023u);
  const float4* zr = (const float4*)(z_t + (size_t)n * DIM);
  const float4* c0 = (const float4*)(cb + ks[0] * DIM);
  const float4* c1 = (const float4*)(cb + ks[1] * DIM);
  const float4* c2 = (const float4*)(cb + ks[2] * DIM);
  const float4* c3 = (const float4*)(cb + ks[3] * DIM);
  double d0 = 0.0, d1 = 0.0, d2 = 0.0, d3 = 0.0;
#pragma unroll 4
  for (int j = 0; j < DIM / 4; ++j) {
    const float4 zv = zr[j];
    const double zx = zv.x, zy = zv.y, zz = zv.z, zw = zv.w;
    const float4 a = c0[j];
    d0 = fma(zx, (double)a.x, d0); d0 = fma(zy, (double)a.y, d0);
    d0 = fma(zz, (double)a.z, d0); d0 = fma(zw, (double)a.w, d0);
    const float4 b = c1[j];
    d1 = fma(zx, (double)b.x, d1); d1 = fma(zy, (double)b.y, d1);
    d1 = fma(zz, (double)b.z, d1); d1 = fma(zw, (double)b.w, d1);
    const float4 c = c2[j];
    d2 = fma(zx, (double)c.x, d2); d2 = fma(zy, (double)c.y, d2);
    d2 = fma(zz, (double)c.z, d2); d2 = fma(zw, (double)c.w, d2);
    const float4 e = c3[j];
    d3 = fma(zx, (double)e.x, d3); d3 = fma(zy, (double)e.y, d3);
    d3 = fma(zz, (double)e.z, d3); d3 = fma(zw, (double)e.w, d3);
  }
  double s[4];
  s[0] = fma(-2.0, d0, cc64[ks[0]]);
  s[1] = fma(-2.0, d1, cc64[ks[1]]);
  s[2] = fma(-2.0, d2, cc64[ks[2]]);
  s[3] = fma(-2.0, d3, cc64[ks[3]]);
  int kw = ks[0]; double sw = s[0];
#pragma unroll
  for (int c = 1; c < 4; ++c) {
    if (s[c] < sw || (s[c] == sw && ks[c] < kw)) { sw = s[c]; kw = ks[c]; }
  }
  out1[n] = (float)kw;
  atomicAdd(&h[kw], 1);
  __syncthreads();
#pragma unroll
  for (int j = 0; j < 4; ++j) {
    const int v = h[tid + 256 * j];
    if (v) atomicAdd(&hist[tid + 256 * j], v);
  }
}

// ---- exclusive scan over 1024 bins + out5 + ntot (single block) -----------
__global__ void k_scan(const int* __restrict__ hist, const float* __restrict__ emc,
                       int* __restrict__ cursor, float* __restrict__ out5,
                       float* __restrict__ ntot) {
  __shared__ int tmp[KCB];
  __shared__ float red[16];
  const int t = threadIdx.x;
  const int v = hist[t];
  tmp[t] = v;
  __syncthreads();
  for (int off = 1; off < KCB; off <<= 1) {
    int x = 0;
    if (t >= off) x = tmp[t - off];
    __syncthreads();
    if (t >= off) tmp[t] += x;
    __syncthreads();
  }
  cursor[t] = tmp[t] - v;
  float o5 = 0.99f * emc[t] + 0.01f * (float)v;
  out5[t] = o5;
#pragma unroll
  for (int m = 32; m; m >>= 1) o5 += __shfl_xor(o5, m, 64);
  if ((t & 63) == 0) red[t >> 6] = o5;
  __syncthreads();
  if (t == 0) {
    float s = 0.f;
#pragma unroll
    for (int j = 0; j < 16; ++j) s += red[j];
    *ntot = s;
  }
}

// ---------------- scatter n's into per-code segments (+ key) ---------------
__global__ void k_scatter(const float* __restrict__ idx_f, int* __restrict__ cursor,
                          int* __restrict__ order, int* __restrict__ key) {
  const int n = blockIdx.x * blockDim.x + threadIdx.x;
  const int k = (int)idx_f[n];
  const int pos = atomicAdd(&cursor[k], 1);
  order[pos] = n;
  key[pos] = k;
}

// ---- chunk-parallel segmented reduce + quantized write + loss partial -----
__global__ __launch_bounds__(128) void k_chunkreduce_q(
    float* zq, const float* __restrict__ cb,
    const int* __restrict__ order, const int* __restrict__ key,
    float* __restrict__ out6, float* __restrict__ lossp) {
  __shared__ int so[CHUNK], sk[CHUNK];
  __shared__ float red[2];
  const int t = threadIdx.x;
  const int base = blockIdx.x * CHUNK;
  if (t < CHUNK) { so[t] = order[base + t]; sk[t] = key[base + t]; }
  __syncthreads();
  int kprev = sk[0];
  float cbv = cb[kprev * 128 + t];
  float acc = 0.f, loss = 0.f;
  int i = 0;
  while (i < CHUNK) {
    if (i + 8 <= CHUNK && sk[i] == kprev && sk[i + 7] == kprev) {
      const int n0 = so[i + 0], n1 = so[i + 1], n2 = so[i + 2], n3 = so[i + 3];
      const int n4 = so[i + 4], n5 = so[i + 5], n6 = so[i + 6], n7 = so[i + 7];
      const float v0 = zq[(size_t)n0 * 128 + t];
      const float v1 = zq[(size_t)n1 * 128 + t];
      const float v2 = zq[(size_t)n2 * 128 + t];
      const float v3 = zq[(size_t)n3 * 128 + t];
      const float v4 = zq[(size_t)n4 * 128 + t];
      const float v5 = zq[(size_t)n5 * 128 + t];
      const float v6 = zq[(size_t)n6 * 128 + t];
      const float v7 = zq[(size_t)n7 * 128 + t];
      acc += ((v0 + v1) + (v2 + v3)) + ((v4 + v5) + (v6 + v7));
      float e;
      e = cbv - v0; loss = fmaf(e, e, loss);
      e = cbv - v1; loss = fmaf(e, e, loss);
      e = cbv - v2; loss = fmaf(e, e, loss);
      e = cbv - v3; loss = fmaf(e, e, loss);
      e = cbv - v4; loss = fmaf(e, e, loss);
      e = cbv - v5; loss = fmaf(e, e, loss);
      e = cbv - v6; loss = fmaf(e, e, loss);
      e = cbv - v7; loss = fmaf(e, e, loss);
      zq[(size_t)n0 * 128 + t] = cbv; zq[(size_t)n1 * 128 + t] = cbv;
      zq[(size_t)n2 * 128 + t] = cbv; zq[(size_t)n3 * 128 + t] = cbv;
      zq[(size_t)n4 * 128 + t] = cbv; zq[(size_t)n5 * 128 + t] = cbv;
      zq[(size_t)n6 * 128 + t] = cbv; zq[(size_t)n7 * 128 + t] = cbv;
      i += 8;
    } else {
      const int kk = sk[i];
      if (kk != kprev) {
        atomicAdd(&out6[kprev * 128 + t], 0.01f * acc);
        acc = 0.f; kprev = kk;
        cbv = cb[kk * 128 + t];
      }
      const int n = so[i];
      const float v = zq[(size_t)n * 128 + t];
      acc += v;
      const float e = cbv - v; loss = fmaf(e, e, loss);
      zq[(size_t)n * 128 + t] = cbv;
      ++i;
    }
  }
  atomicAdd(&out6[kprev * 128 + t], 0.01f * acc);
#pragma unroll
  for (int m = 32; m; m >>= 1) loss += __shfl_xor(loss, m, 64);
  if ((t & 63) == 0) red[t >> 6] = loss;
  __syncthreads();
  if (t == 0) lossp[blockIdx.x] = red[0] + red[1];
}

// ---------------- new_codebook + losses (block 511 reduces partials) -------
__global__ void k_final(const float* __restrict__ out5, const float* __restrict__ out6,
                        const float* __restrict__ ntot_p, const float* __restrict__ lossp,
                        float* __restrict__ out4, float* __restrict__ out2,
                        float* __restrict__ out3) {
  __shared__ float red[4];
  const int i = blockIdx.x * blockDim.x + threadIdx.x;
  const float ntot = *ntot_p;
  const int k = i >> 7;
  const float w = (out5[k] + 1e-5f) / (ntot + KCB * 1e-5f) * ntot;
  out4[i] = out6[i] / w;
  if (blockIdx.x == 511) {
    const int t = threadIdx.x;
    float s = 0.f;
#pragma unroll
    for (int j = 0; j < NCHUNKS / 256; ++j) s += lossp[t + 256 * j];
#pragma unroll
    for (int m = 32; m; m >>= 1) s += __shfl_xor(s, m, 64);
    if ((t & 63) == 0) red[t >> 6] = s;
    __syncthreads();
    if (t == 0) {
      const float lv = (red[0] + red[1] + red[2] + red[3]) * (1.f / 8388608.f);
      *out2 = lv; *out3 = lv;
    }
  }
}

extern "C" void kernel_launch(void* const* d_in, const int* in_sizes, int n_in,
                              void* d_out, int out_size, void* d_ws, size_t ws_size,
                              hipStream_t stream) {
  (void)in_sizes; (void)n_in; (void)out_size; (void)ws_size;
  const float* z   = (const float*)d_in[0];
  const float* cb  = (const float*)d_in[1];
  const float* emc = (const float*)d_in[2];
  const float* emw = (const float*)d_in[3];
  float* out = (float*)d_out;
  float* out0 = out;                    // quantized_st  [8388608]
  float* out1 = out + 8388608;          // idx_map (float)[65536]
  float* out2 = out + 8454144;          // commitment_loss [1]
  float* out3 = out + 8454145;          // codebook_loss   [1]
  float* out4 = out + 8454146;          // new_codebook  [131072]
  float* out5 = out + 8585218;          // new_ema_count [1024]
  float* out6 = out + 8586242;          // new_ema_weight[131072]
  float* ws = (float*)d_ws;
  uint4* cbt      = (uint4*)ws;         // [16384] uint4 = 256KB
  // pcand [2*NVEC] uint2 = 1MB, aliases order/key (scatter runs after rescore)
  uint2* pcand    = (uint2*)(ws + 65536);
  int* order      = (int*)(ws + 65536); // [65536]
  int* key        = (int*)(ws + 131072);// [65536]  (pcand spans through 327680)
  float* ccb      = ws + 327680;        // [1024]
  int* hist       = (int*)(ws + 328704);// [1024]
  int* cursor     = (int*)(ws + 329728);// [1024]
  float* ntot     = ws + 330752;        // [1]
  float* lossp    = ws + 331776;        // [1024]
  double* cc64    = (double*)(ws + 333824);  // [1024] doubles (8B-aligned)
  float* z_t = out0;                    // z_t aliases out0 (overwritten in chunkreduce_q)

  hipLaunchKernelGGL(k_prep, dim3(64), dim3(256), 0, stream, cb, emw, cbt, ccb,
                     cc64, out6, hist);
  hipLaunchKernelGGL(k_argmin4, dim3(NVEC / 64), dim3(256), 0, stream,
                     z, cbt, ccb, pcand, z_t);
  hipLaunchKernelGGL(k_rescore_hist, dim3(NVEC / 256), dim3(256), 0, stream,
                     z_t, cb, cc64, pcand, out1, hist);
  hipLaunchKernelGGL(k_scan, dim3(1), dim3(1024), 0, stream, hist, emc, cursor,
                     out5, ntot);
  hipLaunchKernelGGL(k_scatter, dim3(NVEC / 256), dim3(256), 0, stream, out1, cursor,
                     order, key);
  hipLaunchKernelGGL(k_chunkreduce_q, dim3(NCHUNKS), dim3(128), 0, stream,
                     z_t, cb, order, key, out6, lossp);
  hipLaunchKernelGGL(k_final, dim3(512), dim3(256), 0, stream, out5, out6, ntot,
                     lossp, out4, out2, out3);
}

// Round 13
// 144.137 us; speedup vs baseline: 2.7225x; 2.7225x over previous
//
#include <hip/hip_runtime.h>

#define NVEC 65536   // B*H*W = 64*32*32
#define KCB  1024
#define DIM  128
#define HW   1024    // H*W
#define CHUNK 64
#define NCHUNKS (NVEC / CHUNK)

typedef __bf16 b16;
typedef b16 b16x8 __attribute__((ext_vector_type(8)));
typedef float f32x16 __attribute__((ext_vector_type(16)));

static __device__ __forceinline__ unsigned short f2bf(float f) {
  unsigned int x = __float_as_uint(f);
  unsigned int r = x + 0x7fffu + ((x >> 16) & 1u);   // RNE
  return (unsigned short)(r >> 16);
}

// ---- fused prep: cbt pack + out6=0.99*emw + hist=0 + ccb(f32) + cc64(f64) -
__global__ void k_prep(const float* __restrict__ cb, const float* __restrict__ emw,
                       uint4* __restrict__ cbt, float* __restrict__ ccb,
                       double* __restrict__ cc64, float* __restrict__ out6,
                       int* __restrict__ hist) {
  const int t = blockIdx.x * blockDim.x + threadIdx.x;   // 16384
  const int kc = t >> 11, u = t & 2047;
  const int code7 = u & 127, dch = u >> 7;
  const float* src = cb + (kc * 128 + code7) * 128 + dch * 8;
  const float4 x = *(const float4*)src;
  const float4 y = *(const float4*)(src + 4);
  uint4 o;
  o.x = (unsigned)f2bf(x.x) | ((unsigned)f2bf(x.y) << 16);
  o.y = (unsigned)f2bf(x.z) | ((unsigned)f2bf(x.w) << 16);
  o.z = (unsigned)f2bf(y.x) | ((unsigned)f2bf(y.y) << 16);
  o.w = (unsigned)f2bf(y.z) | ((unsigned)f2bf(y.w) << 16);
  cbt[t] = o;
  // out6 init: out6 offset is 8B- but not 16B-aligned -> float2 stores
  const float4 e0 = *(const float4*)(emw + (size_t)t * 8);
  const float4 e1 = *(const float4*)(emw + (size_t)t * 8 + 4);
  *(float2*)(out6 + (size_t)t * 8 + 0) = make_float2(0.99f * e0.x, 0.99f * e0.y);
  *(float2*)(out6 + (size_t)t * 8 + 2) = make_float2(0.99f * e0.z, 0.99f * e0.w);
  *(float2*)(out6 + (size_t)t * 8 + 4) = make_float2(0.99f * e1.x, 0.99f * e1.y);
  *(float2*)(out6 + (size_t)t * 8 + 6) = make_float2(0.99f * e1.z, 0.99f * e1.w);
  if (t < KCB) hist[t] = 0;
  if (blockIdx.x < 4) {
    const int k = blockIdx.x * 256 + threadIdx.x;
    const float* row = cb + k * DIM;
    double s = 0.0;
#pragma unroll 8
    for (int j = 0; j < DIM; ++j) {
      const double v = (double)row[j];
      s = fma(v, v, s);
    }
    cc64[k] = s;
    ccb[k] = 512.f - 0.5f * (float)s;   // bias keeps packed scores positive
  }
}

// ---- MFMA argmin + fused transpose; paired double-buffer, no reg arrays ---
// R11 post-mortem: runtime-indexed ccv[c] (rule #20) -> scratch -> 560MB
// spill traffic. This version keeps R8's register profile (scalar ccb loads,
// arrays only in unrolled loops) and pipelines with STATIC buffer names:
//   stage(0->Bs0); for p: {bar; stage(2p+1->Bs1); compute(2p,Bs0);
//                          bar; if(p<7) stage(2p+2->Bs0); compute(2p+1,Bs1);}
// Each barrier drains a stage whose latency was hidden by the prior compute.
__global__ __launch_bounds__(256, 4) void k_argmin5(
    const float* __restrict__ z, const uint4* __restrict__ cbt,
    const float* __restrict__ ccb, uint2* __restrict__ pcand,
    float* __restrict__ z_t) {
  __shared__ __align__(16) float zs[128][65];          // 33.3 KB; reused as B bufs
  uint4* Bs0 = (uint4*)zs;                             // [16 dch][64] = 16 KB
  uint4* Bs1 = ((uint4*)zs) + 1024;                    // second 16 KB
  const int tid = threadIdx.x;
  const int l = tid & 63, wv = tid >> 6;
  const int g = l >> 5;                            // k-slice group
  const int lm = l & 31;                           // row-lane / code-lane
  const int wr = (wv & 1) * 32;                    // row group
  const int cg = wv >> 1;                          // code col-group in chunk
  const int n0 = blockIdx.x * 64;
  const int b = n0 >> 10;
  const int hwbase = n0 & (HW - 1);

  // ---- phase 0: coalesced stage of the z tile into LDS
  {
    const int hw4 = (tid & 15) * 4;
    const int dr = tid >> 4;
    const float* src = z + (size_t)b * 131072 + hwbase + hw4;
#pragma unroll
    for (int j = 0; j < 8; ++j) {
      const int d = dr + 16 * j;
      const float4 v = *(const float4*)(src + d * 1024);
      zs[d][hw4 + 0] = v.x; zs[d][hw4 + 1] = v.y;
      zs[d][hw4 + 2] = v.z; zs[d][hw4 + 3] = v.w;
    }
  }
  __syncthreads();

  // ---- phase 1a: z_t rows, full-line stores (8 lanes x 16B per 512B row)
#pragma unroll
  for (int jj = 0; jj < 2; ++jj) {
    const int row = (tid >> 3) + 32 * jj;
    float* dst = z_t + ((size_t)(n0 + row)) * 128;
#pragma unroll
    for (int j = 0; j < 4; ++j) {
      const int d = (j * 8 + (tid & 7)) * 4;
      float4 v;
      v.x = zs[d + 0][row]; v.y = zs[d + 1][row];
      v.z = zs[d + 2][row]; v.w = zs[d + 3][row];
      *(float4*)(dst + d) = v;
    }
  }
  // ---- phase 1b: afrag from LDS
  uint4 afrag[8];
  {
    const int row = wr + lm;
#pragma unroll
    for (int ks = 0; ks < 8; ++ks) {
      const int d0 = ks * 16 + g * 8;
      afrag[ks].x = (unsigned)f2bf(zs[d0 + 0][row]) | ((unsigned)f2bf(zs[d0 + 1][row]) << 16);
      afrag[ks].y = (unsigned)f2bf(zs[d0 + 2][row]) | ((unsigned)f2bf(zs[d0 + 3][row]) << 16);
      afrag[ks].z = (unsigned)f2bf(zs[d0 + 4][row]) | ((unsigned)f2bf(zs[d0 + 5][row]) << 16);
      afrag[ks].w = (unsigned)f2bf(zs[d0 + 6][row]) | ((unsigned)f2bf(zs[d0 + 7][row]) << 16);
    }
  }

  unsigned pm1[16], pm2[16];
#pragma unroll
  for (int r = 0; r < 16; ++r) { pm1[r] = 0u; pm2[r] = 0u; }

  __syncthreads();                     // zs reads done; B bufs may overwrite
  // prologue: stage chunk 0 (kc=0, half=0) into Bs0
#pragma unroll
  for (int i = 0; i < 4; ++i) {
    const int dch = wv * 4 + i;
    __builtin_amdgcn_global_load_lds(&cbt[dch * 128 + l], &Bs0[dch * 64], 16, 0, 0);
  }

#define COMPUTE_CHUNK(CIDX, BUF)                                               \
  {                                                                            \
    const int cbase = (CIDX) * 64 + cg * 32 + lm;                              \
    const float cv = ccb[cbase];                                               \
    f32x16 acc;                                                                \
    _Pragma("unroll")                                                          \
    for (int j = 0; j < 16; ++j) acc[j] = cv;                                  \
    _Pragma("unroll")                                                          \
    for (int ks = 0; ks < 8; ++ks) {                                           \
      const b16x8 av = *reinterpret_cast<const b16x8*>(&afrag[ks]);            \
      const b16x8 bv = *reinterpret_cast<const b16x8*>(                        \
          &(BUF)[(ks * 2 + g) * 64 + cg * 32 + lm]);                           \
      acc = __builtin_amdgcn_mfma_f32_32x32x16_bf16(av, bv, acc, 0, 0, 0);     \
    }                                                                          \
    const unsigned ci = 1023u - (unsigned)cbase;                               \
    _Pragma("unroll")                                                          \
    for (int r = 0; r < 16; ++r) {                                             \
      const unsigned uu = ((__float_as_uint(acc[r]) + 0x200u) & 0xFFFFFC00u) | ci; \
      const unsigned tt = pm1[r] < uu ? pm1[r] : uu;                           \
      pm1[r] = pm1[r] > uu ? pm1[r] : uu;                                      \
      pm2[r] = pm2[r] > tt ? pm2[r] : tt;                                      \
    }                                                                          \
  }

  for (int p = 0; p < 8; ++p) {
    const int c0 = 2 * p, c1 = 2 * p + 1;
    __syncthreads();                   // drains stage(c0) -> Bs0 ready
    {                                  // stage c1 -> Bs1 (hidden under compute)
      const int kc = c1 >> 1, half = c1 & 1;
#pragma unroll
      for (int i = 0; i < 4; ++i) {
        const int dch = wv * 4 + i;
        __builtin_amdgcn_global_load_lds(&cbt[kc * 2048 + dch * 128 + half * 64 + l],
                                         &Bs1[dch * 64], 16, 0, 0);
      }
    }
    COMPUTE_CHUNK(c0, Bs0)
    __syncthreads();                   // drains stage(c1) -> Bs1 ready
    if (p < 7) {                       // stage c0 of next pair -> Bs0
      const int c2 = 2 * p + 2;
      const int kc = c2 >> 1, half = c2 & 1;
#pragma unroll
      for (int i = 0; i < 4; ++i) {
        const int dch = wv * 4 + i;
        __builtin_amdgcn_global_load_lds(&cbt[kc * 2048 + dch * 128 + half * 64 + l],
                                         &Bs0[dch * 64], 16, 0, 0);
      }
    }
    COMPUTE_CHUNK(c1, Bs1)
  }
#undef COMPUTE_CHUNK

  // top-2 (max-order) merge across the 32 code-lanes
#pragma unroll
  for (int r = 0; r < 16; ++r) {
    unsigned u1 = pm1[r], u2 = pm2[r];
#pragma unroll
    for (int m = 1; m < 32; m <<= 1) {
      const unsigned o1 = (unsigned)__shfl_xor((int)u1, m, 64);
      const unsigned o2 = (unsigned)__shfl_xor((int)u2, m, 64);
      const unsigned s = u1 < o1 ? u1 : o1;
      u1 = u1 > o1 ? u1 : o1;
      u2 = u2 > o2 ? u2 : o2;
      u2 = u2 > s ? u2 : s;
    }
    if (lm == 0) {
      const int rowg = n0 + wr + (r & 3) + 8 * (r >> 2) + 4 * g;
      pcand[cg * NVEC + rowg] = make_uint2(u1, u2);
    }
  }
}

// ---- exact f64 rescore of ALL 4 candidates + idx + LDS histogram ----------
__global__ void k_rescore_hist(const float* __restrict__ z_t, const float* __restrict__ cb,
                               const double* __restrict__ cc64,
                               const uint2* __restrict__ pcand,
                               float* __restrict__ out1, int* __restrict__ hist) {
  __shared__ int h[KCB];
  const int tid = threadIdx.x;
#pragma unroll
  for (int j = 0; j < 4; ++j) h[tid + 256 * j] = 0;
  __syncthreads();
  const int n = blockIdx.x * 256 + tid;
  const uint2 A = pcand[n];
  const uint2 Bq = pcand[NVEC + n];
  int ks[4];
  ks[0] = 1023 - (int)(A.x & 1023u);
  ks[1] = 1023 - (int)(A.y & 1023u);
  ks[2] = 1023 - (int)(Bq.x & 1023u);
  ks[3] = 1023 - (int)(Bq.y & 1023u);
  const float4* zr = (const float4*)(z_t + (size_t)n * DIM);
  const float4* c0 = (const float4*)(cb + ks[0] * DIM);
  const float4* c1 = (const float4*)(cb + ks[1] * DIM);
  const float4* c2 = (const float4*)(cb + ks[2] * DIM);
  const float4* c3 = (const float4*)(cb + ks[3] * DIM);
  double d0 = 0.0, d1 = 0.0, d2 = 0.0, d3 = 0.0;
#pragma unroll 4
  for (int j = 0; j < DIM / 4; ++j) {
    const float4 zv = zr[j];
    const double zx = zv.x, zy = zv.y, zz = zv.z, zw = zv.w;
    const float4 a = c0[j];
    d0 = fma(zx, (double)a.x, d0); d0 = fma(zy, (double)a.y, d0);
    d0 = fma(zz, (double)a.z, d0); d0 = fma(zw, (double)a.w, d0);
    const float4 b = c1[j];
    d1 = fma(zx, (double)b.x, d1); d1 = fma(zy, (double)b.y, d1);
    d1 = fma(zz, (double)b.z, d1); d1 = fma(zw, (double)b.w, d1);
    const float4 c = c2[j];
    d2 = fma(zx, (double)c.x, d2); d2 = fma(zy, (double)c.y, d2);
    d2 = fma(zz, (double)c.z, d2); d2 = fma(zw, (double)c.w, d2);
    const float4 e = c3[j];
    d3 = fma(zx, (double)e.x, d3); d3 = fma(zy, (double)e.y, d3);
    d3 = fma(zz, (double)e.z, d3); d3 = fma(zw, (double)e.w, d3);
  }
  double s[4];
  s[0] = fma(-2.0, d0, cc64[ks[0]]);
  s[1] = fma(-2.0, d1, cc64[ks[1]]);
  s[2] = fma(-2.0, d2, cc64[ks[2]]);
  s[3] = fma(-2.0, d3, cc64[ks[3]]);
  int kw = ks[0]; double sw = s[0];
#pragma unroll
  for (int c = 1; c < 4; ++c) {
    if (s[c] < sw || (s[c] == sw && ks[c] < kw)) { sw = s[c]; kw = ks[c]; }
  }
  out1[n] = (float)kw;
  atomicAdd(&h[kw], 1);
  __syncthreads();
#pragma unroll
  for (int j = 0; j < 4; ++j) {
    const int v = h[tid + 256 * j];
    if (v) atomicAdd(&hist[tid + 256 * j], v);
  }
}

// ---- exclusive scan over 1024 bins + out5 + ntot (single block) -----------
__global__ void k_scan(const int* __restrict__ hist, const float* __restrict__ emc,
                       int* __restrict__ cursor, float* __restrict__ out5,
                       float* __restrict__ ntot) {
  __shared__ int tmp[KCB];
  __shared__ float red[16];
  const int t = threadIdx.x;
  const int v = hist[t];
  tmp[t] = v;
  __syncthreads();
  for (int off = 1; off < KCB; off <<= 1) {
    int x = 0;
    if (t >= off) x = tmp[t - off];
    __syncthreads();
    if (t >= off) tmp[t] += x;
    __syncthreads();
  }
  cursor[t] = tmp[t] - v;
  float o5 = 0.99f * emc[t] + 0.01f * (float)v;
  out5[t] = o5;
#pragma unroll
  for (int m = 32; m; m >>= 1) o5 += __shfl_xor(o5, m, 64);
  if ((t & 63) == 0) red[t >> 6] = o5;
  __syncthreads();
  if (t == 0) {
    float s = 0.f;
#pragma unroll
    for (int j = 0; j < 16; ++j) s += red[j];
    *ntot = s;
  }
}

// ---------------- scatter n's into per-code segments (+ key) ---------------
__global__ void k_scatter(const float* __restrict__ idx_f, int* __restrict__ cursor,
                          int* __restrict__ order, int* __restrict__ key) {
  const int n = blockIdx.x * blockDim.x + threadIdx.x;
  const int k = (int)idx_f[n];
  const int pos = atomicAdd(&cursor[k], 1);
  order[pos] = n;
  key[pos] = k;
}

// ---- chunk-parallel segmented reduce + quantized write + loss partial -----
__global__ __launch_bounds__(128) void k_chunkreduce_q(
    float* zq, const float* __restrict__ cb,
    const int* __restrict__ order, const int* __restrict__ key,
    float* __restrict__ out6, float* __restrict__ lossp) {
  __shared__ int so[CHUNK], sk[CHUNK];
  __shared__ float red[2];
  const int t = threadIdx.x;
  const int base = blockIdx.x * CHUNK;
  if (t < CHUNK) { so[t] = order[base + t]; sk[t] = key[base + t]; }
  __syncthreads();
  int kprev = sk[0];
  float cbv = cb[kprev * 128 + t];
  float acc = 0.f, loss = 0.f;
  int i = 0;
  while (i < CHUNK) {
    if (i + 8 <= CHUNK && sk[i] == kprev && sk[i + 7] == kprev) {
      const int n0 = so[i + 0], n1 = so[i + 1], n2 = so[i + 2], n3 = so[i + 3];
      const int n4 = so[i + 4], n5 = so[i + 5], n6 = so[i + 6], n7 = so[i + 7];
      const float v0 = zq[(size_t)n0 * 128 + t];
      const float v1 = zq[(size_t)n1 * 128 + t];
      const float v2 = zq[(size_t)n2 * 128 + t];
      const float v3 = zq[(size_t)n3 * 128 + t];
      const float v4 = zq[(size_t)n4 * 128 + t];
      const float v5 = zq[(size_t)n5 * 128 + t];
      const float v6 = zq[(size_t)n6 * 128 + t];
      const float v7 = zq[(size_t)n7 * 128 + t];
      acc += ((v0 + v1) + (v2 + v3)) + ((v4 + v5) + (v6 + v7));
      float e;
      e = cbv - v0; loss = fmaf(e, e, loss);
      e = cbv - v1; loss = fmaf(e, e, loss);
      e = cbv - v2; loss = fmaf(e, e, loss);
      e = cbv - v3; loss = fmaf(e, e, loss);
      e = cbv - v4; loss = fmaf(e, e, loss);
      e = cbv - v5; loss = fmaf(e, e, loss);
      e = cbv - v6; loss = fmaf(e, e, loss);
      e = cbv - v7; loss = fmaf(e, e, loss);
      zq[(size_t)n0 * 128 + t] = cbv; zq[(size_t)n1 * 128 + t] = cbv;
      zq[(size_t)n2 * 128 + t] = cbv; zq[(size_t)n3 * 128 + t] = cbv;
      zq[(size_t)n4 * 128 + t] = cbv; zq[(size_t)n5 * 128 + t] = cbv;
      zq[(size_t)n6 * 128 + t] = cbv; zq[(size_t)n7 * 128 + t] = cbv;
      i += 8;
    } else {
      const int kk = sk[i];
      if (kk != kprev) {
        atomicAdd(&out6[kprev * 128 + t], 0.01f * acc);
        acc = 0.f; kprev = kk;
        cbv = cb[kk * 128 + t];
      }
      const int n = so[i];
      const float v = zq[(size_t)n * 128 + t];
      acc += v;
      const float e = cbv - v; loss = fmaf(e, e, loss);
      zq[(size_t)n * 128 + t] = cbv;
      ++i;
    }
  }
  atomicAdd(&out6[kprev * 128 + t], 0.01f * acc);
#pragma unroll
  for (int m = 32; m; m >>= 1) loss += __shfl_xor(loss, m, 64);
  if ((t & 63) == 0) red[t >> 6] = loss;
  __syncthreads();
  if (t == 0) lossp[blockIdx.x] = red[0] + red[1];
}

// ---------------- new_codebook + losses (block 511 reduces partials) -------
__global__ void k_final(const float* __restrict__ out5, const float* __restrict__ out6,
                        const float* __restrict__ ntot_p, const float* __restrict__ lossp,
                        float* __restrict__ out4, float* __restrict__ out2,
                        float* __restrict__ out3) {
  __shared__ float red[4];
  const int i = blockIdx.x * blockDim.x + threadIdx.x;
  const float ntot = *ntot_p;
  const int k = i >> 7;
  const float w = (out5[k] + 1e-5f) / (ntot + KCB * 1e-5f) * ntot;
  out4[i] = out6[i] / w;
  if (blockIdx.x == 511) {
    const int t = threadIdx.x;
    float s = 0.f;
#pragma unroll
    for (int j = 0; j < NCHUNKS / 256; ++j) s += lossp[t + 256 * j];
#pragma unroll
    for (int m = 32; m; m >>= 1) s += __shfl_xor(s, m, 64);
    if ((t & 63) == 0) red[t >> 6] = s;
    __syncthreads();
    if (t == 0) {
      const float lv = (red[0] + red[1] + red[2] + red[3]) * (1.f / 8388608.f);
      *out2 = lv; *out3 = lv;
    }
  }
}

extern "C" void kernel_launch(void* const* d_in, const int* in_sizes, int n_in,
                              void* d_out, int out_size, void* d_ws, size_t ws_size,
                              hipStream_t stream) {
  (void)in_sizes; (void)n_in; (void)out_size; (void)ws_size;
  const float* z   = (const float*)d_in[0];
  const float* cb  = (const float*)d_in[1];
  const float* emc = (const float*)d_in[2];
  const float* emw = (const float*)d_in[3];
  float* out = (float*)d_out;
  float* out0 = out;                    // quantized_st  [8388608]
  float* out1 = out + 8388608;          // idx_map (float)[65536]
  float* out2 = out + 8454144;          // commitment_loss [1]
  float* out3 = out + 8454145;          // codebook_loss   [1]
  float* out4 = out + 8454146;          // new_codebook  [131072]
  float* out5 = out + 8585218;          // new_ema_count [1024]
  float* out6 = out + 8586242;          // new_ema_weight[131072]
  float* ws = (float*)d_ws;
  uint4* cbt      = (uint4*)ws;         // [16384] uint4 = 256KB
  // pcand [2*NVEC] uint2 = 1MB, aliases order/key (scatter runs after rescore)
  uint2* pcand    = (uint2*)(ws + 65536);
  int* order      = (int*)(ws + 65536); // [65536]
  int* key        = (int*)(ws + 131072);// [65536]  (pcand spans through 327680)
  float* ccb      = ws + 327680;        // [1024]
  int* hist       = (int*)(ws + 328704);// [1024]
  int* cursor     = (int*)(ws + 329728);// [1024]
  float* ntot     = ws + 330752;        // [1]
  float* lossp    = ws + 331776;        // [1024]
  double* cc64    = (double*)(ws + 333824);  // [1024] doubles (8B-aligned)
  float* z_t = out0;                    // z_t aliases out0 (overwritten in chunkreduce_q)

  hipLaunchKernelGGL(k_prep, dim3(64), dim3(256), 0, stream, cb, emw, cbt, ccb,
                     cc64, out6, hist);
  hipLaunchKernelGGL(k_argmin5, dim3(NVEC / 64), dim3(256), 0, stream,
                     z, cbt, ccb, pcand, z_t);
  hipLaunchKernelGGL(k_rescore_hist, dim3(NVEC / 256), dim3(256), 0, stream,
                     z_t, cb, cc64, pcand, out1, hist);
  hipLaunchKernelGGL(k_scan, dim3(1), dim3(1024), 0, stream, hist, emc, cursor,
                     out5, ntot);
  hipLaunchKernelGGL(k_scatter, dim3(NVEC / 256), dim3(256), 0, stream, out1, cursor,
                     order, key);
  hipLaunchKernelGGL(k_chunkreduce_q, dim3(NCHUNKS), dim3(128), 0, stream,
                     z_t, cb, order, key, out6, lossp);
  hipLaunchKernelGGL(k_final, dim3(512), dim3(256), 0, stream, out5, out6, ntot,
                     lossp, out4, out2, out3);
}

// Round 14
// 129.774 us; speedup vs baseline: 3.0238x; 1.1107x over previous
//
#include <hip/hip_runtime.h>

#define NVEC 65536   // B*H*W = 64*32*32
#define KCB  1024
#define DIM  128
#define HW   1024    // H*W
#define CHUNK 64
#define NCHUNKS (NVEC / CHUNK)

typedef __bf16 b16;
typedef b16 b16x8 __attribute__((ext_vector_type(8)));
typedef float f32x16 __attribute__((ext_vector_type(16)));

static __device__ __forceinline__ unsigned short f2bf(float f) {
  unsigned int x = __float_as_uint(f);
  unsigned int r = x + 0x7fffu + ((x >> 16) & 1u);   // RNE
  return (unsigned short)(r >> 16);
}

// ---- fused prep: cbt pack + out6=0.99*emw + hist=0 + ccb(f32) + cc64(f64) -
__global__ void k_prep(const float* __restrict__ cb, const float* __restrict__ emw,
                       uint4* __restrict__ cbt, float* __restrict__ ccb,
                       double* __restrict__ cc64, float* __restrict__ out6,
                       int* __restrict__ hist) {
  const int t = blockIdx.x * blockDim.x + threadIdx.x;   // 16384
  const int kc = t >> 11, u = t & 2047;
  const int code7 = u & 127, dch = u >> 7;
  const float* src = cb + (kc * 128 + code7) * 128 + dch * 8;
  const float4 x = *(const float4*)src;
  const float4 y = *(const float4*)(src + 4);
  uint4 o;
  o.x = (unsigned)f2bf(x.x) | ((unsigned)f2bf(x.y) << 16);
  o.y = (unsigned)f2bf(x.z) | ((unsigned)f2bf(x.w) << 16);
  o.z = (unsigned)f2bf(y.x) | ((unsigned)f2bf(y.y) << 16);
  o.w = (unsigned)f2bf(y.z) | ((unsigned)f2bf(y.w) << 16);
  cbt[t] = o;
  // out6 init: out6 offset is 8B- but not 16B-aligned -> float2 stores
  const float4 e0 = *(const float4*)(emw + (size_t)t * 8);
  const float4 e1 = *(const float4*)(emw + (size_t)t * 8 + 4);
  *(float2*)(out6 + (size_t)t * 8 + 0) = make_float2(0.99f * e0.x, 0.99f * e0.y);
  *(float2*)(out6 + (size_t)t * 8 + 2) = make_float2(0.99f * e0.z, 0.99f * e0.w);
  *(float2*)(out6 + (size_t)t * 8 + 4) = make_float2(0.99f * e1.x, 0.99f * e1.y);
  *(float2*)(out6 + (size_t)t * 8 + 6) = make_float2(0.99f * e1.z, 0.99f * e1.w);
  if (t < KCB) hist[t] = 0;
  if (blockIdx.x < 4) {
    const int k = blockIdx.x * 256 + threadIdx.x;
    const float* row = cb + k * DIM;
    double s = 0.0;
#pragma unroll 8
    for (int j = 0; j < DIM; ++j) {
      const double v = (double)row[j];
      s = fma(v, v, s);
    }
    cc64[k] = s;
    ccb[k] = 512.f - 0.5f * (float)s;   // bias keeps packed scores positive
  }
}

// ---- MFMA argmin + fused transpose + FUSED f64 rescore/hist ---------------
// Core kc-loop is R8's exact structure (43us, no spill): 8 chunks of 128
// codes, single 32KB Bs buffer, drain-per-chunk. R9-R12 pipelining attempts
// all spilled (rule #20 / register tiles) and lost; do not rearchitect.
// NEW: both code-halves' top-2 live in this block -> rescore in-kernel:
// cand->LDS, thread t rescores cand (t&3) of row (t>>2) in exact f64
// (same accumulation order as the old k_rescore_hist -> bit-identical),
// 4-lane shfl reduce, out1 + LDS-hist (aliasing dead Bs) -> global hist.
// Deletes a kernel, a 32MB z_t re-read, and the 1MB pcand round-trip.
__global__ __launch_bounds__(256, 4) void k_argmin6(
    const float* __restrict__ z, const uint4* __restrict__ cbt,
    const float* __restrict__ ccb, const double* __restrict__ cc64,
    const float* __restrict__ cb, float* __restrict__ z_t,
    float* __restrict__ out1, int* __restrict__ hist) {
  __shared__ __align__(16) float zs[128][65];          // 33.3 KB; reused as Bs, then hist
  __shared__ uint2 cand[64][2];                        // 1 KB candidate exchange
  uint4* Bs = (uint4*)zs;
  const int tid = threadIdx.x;
  const int l = tid & 63, wv = tid >> 6;
  const int g = l >> 5;                            // k-slice group
  const int lm = l & 31;                           // row-lane / code-lane
  const int wr = (wv & 1) * 32;                    // row group
  const int wc = wv >> 1;                          // code half (0..1)
  const int n0 = blockIdx.x * 64;
  const int b = n0 >> 10;
  const int hwbase = n0 & (HW - 1);

  // ---- phase 0: coalesced stage of the z tile into LDS
  {
    const int hw4 = (tid & 15) * 4;
    const int dr = tid >> 4;
    const float* src = z + (size_t)b * 131072 + hwbase + hw4;
#pragma unroll
    for (int j = 0; j < 8; ++j) {
      const int d = dr + 16 * j;
      const float4 v = *(const float4*)(src + d * 1024);
      zs[d][hw4 + 0] = v.x; zs[d][hw4 + 1] = v.y;
      zs[d][hw4 + 2] = v.z; zs[d][hw4 + 3] = v.w;
    }
  }
  __syncthreads();

  // ---- phase 1a: z_t rows, full-line stores (8 lanes x 16B per 512B row)
#pragma unroll
  for (int jj = 0; jj < 2; ++jj) {
    const int row = (tid >> 3) + 32 * jj;
    float* dst = z_t + ((size_t)(n0 + row)) * 128;
#pragma unroll
    for (int j = 0; j < 4; ++j) {
      const int d = (j * 8 + (tid & 7)) * 4;
      float4 v;
      v.x = zs[d + 0][row]; v.y = zs[d + 1][row];
      v.z = zs[d + 2][row]; v.w = zs[d + 3][row];
      *(float4*)(dst + d) = v;
    }
  }
  // ---- phase 1b: afrag from LDS
  uint4 afrag[8];
  {
    const int row = wr + lm;
#pragma unroll
    for (int ks = 0; ks < 8; ++ks) {
      const int d0 = ks * 16 + g * 8;
      afrag[ks].x = (unsigned)f2bf(zs[d0 + 0][row]) | ((unsigned)f2bf(zs[d0 + 1][row]) << 16);
      afrag[ks].y = (unsigned)f2bf(zs[d0 + 2][row]) | ((unsigned)f2bf(zs[d0 + 3][row]) << 16);
      afrag[ks].z = (unsigned)f2bf(zs[d0 + 4][row]) | ((unsigned)f2bf(zs[d0 + 5][row]) << 16);
      afrag[ks].w = (unsigned)f2bf(zs[d0 + 6][row]) | ((unsigned)f2bf(zs[d0 + 7][row]) << 16);
    }
  }

  unsigned pm1[16], pm2[16];
#pragma unroll
  for (int r = 0; r < 16; ++r) { pm1[r] = 0u; pm2[r] = 0u; }

  for (int kc = 0; kc < 8; ++kc) {
    __syncthreads();    // kc=0: zs readers done; kc>0: Bs readers done
#pragma unroll
    for (int i = 0; i < 8; ++i) {
      __builtin_amdgcn_global_load_lds(&cbt[kc * 2048 + wv * 512 + i * 64 + l],
                                       &Bs[wv * 512 + i * 64], 16, 0, 0);
    }
    const float cv0 = ccb[kc * 128 + (wc * 2 + 0) * 32 + lm];
    const float cv1 = ccb[kc * 128 + (wc * 2 + 1) * 32 + lm];
    __syncthreads();                               // staging landed

    f32x16 a0, a1;
#pragma unroll
    for (int j = 0; j < 16; ++j) { a0[j] = cv0; a1[j] = cv1; }
#pragma unroll
    for (int ks = 0; ks < 8; ++ks) {
      const b16x8 av = *reinterpret_cast<const b16x8*>(&afrag[ks]);
      const b16x8 bv0 = *reinterpret_cast<const b16x8*>(&Bs[(ks * 2 + g) * 128 + (wc * 2) * 32 + lm]);
      const b16x8 bv1 = *reinterpret_cast<const b16x8*>(&Bs[(ks * 2 + g) * 128 + (wc * 2 + 1) * 32 + lm]);
      a0 = __builtin_amdgcn_mfma_f32_32x32x16_bf16(av, bv0, a0, 0, 0, 0);
      a1 = __builtin_amdgcn_mfma_f32_32x32x16_bf16(av, bv1, a1, 0, 0, 0);
    }
    const unsigned ci0 = 1023u - (unsigned)(kc * 128 + (wc * 2) * 32 + lm);
    const unsigned ci1 = ci0 - 32u;
#pragma unroll
    for (int r = 0; r < 16; ++r) {
      {
        const unsigned uu = ((__float_as_uint(a0[r]) + 0x200u) & 0xFFFFFC00u) | ci0;
        const unsigned t = pm1[r] < uu ? pm1[r] : uu;
        pm1[r] = pm1[r] > uu ? pm1[r] : uu;
        pm2[r] = pm2[r] > t ? pm2[r] : t;
      }
      {
        const unsigned uu = ((__float_as_uint(a1[r]) + 0x200u) & 0xFFFFFC00u) | ci1;
        const unsigned t = pm1[r] < uu ? pm1[r] : uu;
        pm1[r] = pm1[r] > uu ? pm1[r] : uu;
        pm2[r] = pm2[r] > t ? pm2[r] : t;
      }
    }
  }

  // top-2 (max-order) merge across the 32 code-lanes -> cand LDS
#pragma unroll
  for (int r = 0; r < 16; ++r) {
    unsigned u1 = pm1[r], u2 = pm2[r];
#pragma unroll
    for (int m = 1; m < 32; m <<= 1) {
      const unsigned o1 = (unsigned)__shfl_xor((int)u1, m, 64);
      const unsigned o2 = (unsigned)__shfl_xor((int)u2, m, 64);
      const unsigned s = u1 < o1 ? u1 : o1;
      u1 = u1 > o1 ? u1 : o1;
      u2 = u2 > o2 ? u2 : o2;
      u2 = u2 > s ? u2 : s;
    }
    if (lm == 0) {
      const int lrow = wr + (r & 3) + 8 * (r >> 2) + 4 * g;
      cand[lrow][wc] = make_uint2(u1, u2);
    }
  }
  __syncthreads();                   // compute reads of Bs done; cand visible

  // ---- fused rescore: thread t -> row t>>2, candidate t&3 (exact f64)
  int* h = (int*)zs;                 // hist aliases dead Bs region
#pragma unroll
  for (int j = 0; j < 4; ++j) h[tid + 256 * j] = 0;
  __syncthreads();
  {
    const int row = tid >> 2, c = tid & 3;
    const uint2 cd = cand[row][c >> 1];
    const unsigned u = (c & 1) ? cd.y : cd.x;
    int k = 1023 - (int)(u & 1023u);
    const int n = n0 + row;
    const float4* zr = (const float4*)(z_t + (size_t)n * DIM);
    const float4* cr = (const float4*)(cb + k * DIM);
    double d = 0.0;
#pragma unroll 8
    for (int j = 0; j < DIM / 4; ++j) {
      const float4 zv = zr[j], cv = cr[j];
      d = fma((double)zv.x, (double)cv.x, d);
      d = fma((double)zv.y, (double)cv.y, d);
      d = fma((double)zv.z, (double)cv.z, d);
      d = fma((double)zv.w, (double)cv.w, d);
    }
    double s = fma(-2.0, d, cc64[k]);
#pragma unroll
    for (int m = 1; m < 4; m <<= 1) {
      const double os = __shfl_xor(s, m, 64);
      const int ok = __shfl_xor(k, m, 64);
      if (os < s || (os == s && ok < k)) { s = os; k = ok; }
    }
    if (c == 0) {
      out1[n] = (float)k;
      atomicAdd(&h[k], 1);
    }
  }
  __syncthreads();
#pragma unroll
  for (int j = 0; j < 4; ++j) {
    const int v = h[tid + 256 * j];
    if (v) atomicAdd(&hist[tid + 256 * j], v);
  }
}

// ---- exclusive scan over 1024 bins + out5 + ntot (single block) -----------
__global__ void k_scan(const int* __restrict__ hist, const float* __restrict__ emc,
                       int* __restrict__ cursor, float* __restrict__ out5,
                       float* __restrict__ ntot) {
  __shared__ int tmp[KCB];
  __shared__ float red[16];
  const int t = threadIdx.x;
  const int v = hist[t];
  tmp[t] = v;
  __syncthreads();
  for (int off = 1; off < KCB; off <<= 1) {
    int x = 0;
    if (t >= off) x = tmp[t - off];
    __syncthreads();
    if (t >= off) tmp[t] += x;
    __syncthreads();
  }
  cursor[t] = tmp[t] - v;
  float o5 = 0.99f * emc[t] + 0.01f * (float)v;
  out5[t] = o5;
#pragma unroll
  for (int m = 32; m; m >>= 1) o5 += __shfl_xor(o5, m, 64);
  if ((t & 63) == 0) red[t >> 6] = o5;
  __syncthreads();
  if (t == 0) {
    float s = 0.f;
#pragma unroll
    for (int j = 0; j < 16; ++j) s += red[j];
    *ntot = s;
  }
}

// ---------------- scatter n's into per-code segments (+ key) ---------------
__global__ void k_scatter(const float* __restrict__ idx_f, int* __restrict__ cursor,
                          int* __restrict__ order, int* __restrict__ key) {
  const int n = blockIdx.x * blockDim.x + threadIdx.x;
  const int k = (int)idx_f[n];
  const int pos = atomicAdd(&cursor[k], 1);
  order[pos] = n;
  key[pos] = k;
}

// ---- chunk-parallel segmented reduce + quantized write + loss partial -----
__global__ __launch_bounds__(128) void k_chunkreduce_q(
    float* zq, const float* __restrict__ cb,
    const int* __restrict__ order, const int* __restrict__ key,
    float* __restrict__ out6, float* __restrict__ lossp) {
  __shared__ int so[CHUNK], sk[CHUNK];
  __shared__ float red[2];
  const int t = threadIdx.x;
  const int base = blockIdx.x * CHUNK;
  if (t < CHUNK) { so[t] = order[base + t]; sk[t] = key[base + t]; }
  __syncthreads();
  int kprev = sk[0];
  float cbv = cb[kprev * 128 + t];
  float acc = 0.f, loss = 0.f;
  int i = 0;
  while (i < CHUNK) {
    if (i + 8 <= CHUNK && sk[i] == kprev && sk[i + 7] == kprev) {
      const int n0 = so[i + 0], n1 = so[i + 1], n2 = so[i + 2], n3 = so[i + 3];
      const int n4 = so[i + 4], n5 = so[i + 5], n6 = so[i + 6], n7 = so[i + 7];
      const float v0 = zq[(size_t)n0 * 128 + t];
      const float v1 = zq[(size_t)n1 * 128 + t];
      const float v2 = zq[(size_t)n2 * 128 + t];
      const float v3 = zq[(size_t)n3 * 128 + t];
      const float v4 = zq[(size_t)n4 * 128 + t];
      const float v5 = zq[(size_t)n5 * 128 + t];
      const float v6 = zq[(size_t)n6 * 128 + t];
      const float v7 = zq[(size_t)n7 * 128 + t];
      acc += ((v0 + v1) + (v2 + v3)) + ((v4 + v5) + (v6 + v7));
      float e;
      e = cbv - v0; loss = fmaf(e, e, loss);
      e = cbv - v1; loss = fmaf(e, e, loss);
      e = cbv - v2; loss = fmaf(e, e, loss);
      e = cbv - v3; loss = fmaf(e, e, loss);
      e = cbv - v4; loss = fmaf(e, e, loss);
      e = cbv - v5; loss = fmaf(e, e, loss);
      e = cbv - v6; loss = fmaf(e, e, loss);
      e = cbv - v7; loss = fmaf(e, e, loss);
      zq[(size_t)n0 * 128 + t] = cbv; zq[(size_t)n1 * 128 + t] = cbv;
      zq[(size_t)n2 * 128 + t] = cbv; zq[(size_t)n3 * 128 + t] = cbv;
      zq[(size_t)n4 * 128 + t] = cbv; zq[(size_t)n5 * 128 + t] = cbv;
      zq[(size_t)n6 * 128 + t] = cbv; zq[(size_t)n7 * 128 + t] = cbv;
      i += 8;
    } else {
      const int kk = sk[i];
      if (kk != kprev) {
        atomicAdd(&out6[kprev * 128 + t], 0.01f * acc);
        acc = 0.f; kprev = kk;
        cbv = cb[kk * 128 + t];
      }
      const int n = so[i];
      const float v = zq[(size_t)n * 128 + t];
      acc += v;
      const float e = cbv - v; loss = fmaf(e, e, loss);
      zq[(size_t)n * 128 + t] = cbv;
      ++i;
    }
  }
  atomicAdd(&out6[kprev * 128 + t], 0.01f * acc);
#pragma unroll
  for (int m = 32; m; m >>= 1) loss += __shfl_xor(loss, m, 64);
  if ((t & 63) == 0) red[t >> 6] = loss;
  __syncthreads();
  if (t == 0) lossp[blockIdx.x] = red[0] + red[1];
}

// ---------------- new_codebook + losses (block 511 reduces partials) -------
__global__ void k_final(const float* __restrict__ out5, const float* __restrict__ out6,
                        const float* __restrict__ ntot_p, const float* __restrict__ lossp,
                        float* __restrict__ out4, float* __restrict__ out2,
                        float* __restrict__ out3) {
  __shared__ float red[4];
  const int i = blockIdx.x * blockDim.x + threadIdx.x;
  const float ntot = *ntot_p;
  const int k = i >> 7;
  const float w = (out5[k] + 1e-5f) / (ntot + KCB * 1e-5f) * ntot;
  out4[i] = out6[i] / w;
  if (blockIdx.x == 511) {
    const int t = threadIdx.x;
    float s = 0.f;
#pragma unroll
    for (int j = 0; j < NCHUNKS / 256; ++j) s += lossp[t + 256 * j];
#pragma unroll
    for (int m = 32; m; m >>= 1) s += __shfl_xor(s, m, 64);
    if ((t & 63) == 0) red[t >> 6] = s;
    __syncthreads();
    if (t == 0) {
      const float lv = (red[0] + red[1] + red[2] + red[3]) * (1.f / 8388608.f);
      *out2 = lv; *out3 = lv;
    }
  }
}

extern "C" void kernel_launch(void* const* d_in, const int* in_sizes, int n_in,
                              void* d_out, int out_size, void* d_ws, size_t ws_size,
                              hipStream_t stream) {
  (void)in_sizes; (void)n_in; (void)out_size; (void)ws_size;
  const float* z   = (const float*)d_in[0];
  const float* cb  = (const float*)d_in[1];
  const float* emc = (const float*)d_in[2];
  const float* emw = (const float*)d_in[3];
  float* out = (float*)d_out;
  float* out0 = out;                    // quantized_st  [8388608]
  float* out1 = out + 8388608;          // idx_map (float)[65536]
  float* out2 = out + 8454144;          // commitment_loss [1]
  float* out3 = out + 8454145;          // codebook_loss   [1]
  float* out4 = out + 8454146;          // new_codebook  [131072]
  float* out5 = out + 8585218;          // new_ema_count [1024]
  float* out6 = out + 8586242;          // new_ema_weight[131072]
  float* ws = (float*)d_ws;
  uint4* cbt      = (uint4*)ws;         // [16384] uint4 = 256KB
  int* order      = (int*)(ws + 65536); // [65536]
  int* key        = (int*)(ws + 131072);// [65536]
  float* ccb      = ws + 327680;        // [1024]
  int* hist       = (int*)(ws + 328704);// [1024]
  int* cursor     = (int*)(ws + 329728);// [1024]
  float* ntot     = ws + 330752;        // [1]
  float* lossp    = ws + 331776;        // [1024]
  double* cc64    = (double*)(ws + 333824);  // [1024] doubles (8B-aligned)
  float* z_t = out0;                    // z_t aliases out0 (overwritten in chunkreduce_q)

  hipLaunchKernelGGL(k_prep, dim3(64), dim3(256), 0, stream, cb, emw, cbt, ccb,
                     cc64, out6, hist);
  hipLaunchKernelGGL(k_argmin6, dim3(NVEC / 64), dim3(256), 0, stream,
                     z, cbt, ccb, cc64, cb, z_t, out1, hist);
  hipLaunchKernelGGL(k_scan, dim3(1), dim3(1024), 0, stream, hist, emc, cursor,
                     out5, ntot);
  hipLaunchKernelGGL(k_scatter, dim3(NVEC / 256), dim3(256), 0, stream, out1, cursor,
                     order, key);
  hipLaunchKernelGGL(k_chunkreduce_q, dim3(NCHUNKS), dim3(128), 0, stream,
                     z_t, cb, order, key, out6, lossp);
  hipLaunchKernelGGL(k_final, dim3(512), dim3(256), 0, stream, out5, out6, ntot,
                     lossp, out4, out2, out3);
}